// Round 17
// baseline (212.241 us; speedup 1.0000x reference)
//
#include <hip/hip_runtime.h>
#include <stdint.h>

typedef unsigned short u16;
typedef u16 u16x8 __attribute__((ext_vector_type(8)));
typedef u16 u16x4 __attribute__((ext_vector_type(4)));
typedef short s16x8 __attribute__((ext_vector_type(8)));
typedef float f32x4 __attribute__((ext_vector_type(4)));

#define B_ 4
#define LQ_ 1024
#define LK_ 2048
#define D_ 1024
#define H_ 16
#define DH_ 64
#define QSCL 0.1803368801111204f
#define L2_10000 13.287712379549449f

__device__ __forceinline__ u16 f2bf(float x) {
  uint32_t u = __float_as_uint(x);
  u += 0x7FFFu + ((u >> 16) & 1u);
  return (u16)(u >> 16);
}
__device__ __forceinline__ float bf2f(u16 h) {
  return __uint_as_float(((uint32_t)h) << 16);
}
__device__ __forceinline__ uint32_t cvtpk(float lo, float hi) {
  uint32_t r;
  asm("v_cvt_pk_bf16_f32 %0, %1, %2" : "=v"(r) : "v"(lo), "v"(hi));
  return r;
}
__device__ __forceinline__ float exp2fast(float x) {
  float r;
  asm("v_exp_f32 %0, %1" : "=v"(r) : "v"(x));
  return r;
}

// ---------- merged fp32->bf16 casts for all 5 inputs (one launch) ----------
// blocks: [0,4096) queries | [4096,5120) wq | [5120,13312) kv | [13312,15360) wkv | [15360,16384) wo
__global__ __launch_bounds__(256) void cast5_k(const float* __restrict__ s0, u16* __restrict__ d0,
                                               const float* __restrict__ s1, u16* __restrict__ d1,
                                               const float* __restrict__ s2, u16* __restrict__ d2,
                                               const float* __restrict__ s3, u16* __restrict__ d3,
                                               const float* __restrict__ s4, u16* __restrict__ d4) {
  int b = blockIdx.x;
  const float* s;
  u16* d;
  int base;
  if (b < 4096) { s = s0; d = d0; base = b; }
  else if (b < 5120) { s = s1; d = d1; base = b - 4096; }
  else if (b < 13312) { s = s2; d = d2; base = b - 5120; }
  else if (b < 15360) { s = s3; d = d3; base = b - 13312; }
  else { s = s4; d = d4; base = b - 15360; }
  int i = (base * 256 + threadIdx.x) * 4;
  float4 v = *(const float4*)(s + i);
  ushort4 o;
  o.x = f2bf(v.x); o.y = f2bf(v.y); o.z = f2bf(v.z); o.w = f2bf(v.w);
  *(ushort4*)(d + i) = o;
}

// ---------- 128x128 GEMM, split-K (Q/O), T4 counted-vmcnt double-buffer ----------
__global__ __launch_bounds__(256) void gemm_bt(const u16* __restrict__ A,
                                               const u16* __restrict__ Bm,
                                               float* __restrict__ C,
                                               int N) {
  __shared__ __align__(16) u16 As[2][128 * 32];
  __shared__ __align__(16) u16 Bs[2][128 * 32];
  const int tid = threadIdx.x;
  const int lane = tid & 63;
  const int wid = tid >> 6;
  const int m0 = blockIdx.x * 128;
  const int n0 = blockIdx.y * 128;
  const int slice = 1024 / gridDim.z;
  const int kStart = blockIdx.z * slice;
  const int NT = slice >> 5;
  C += (size_t)blockIdx.z * (size_t)gridDim.x * 128 * N;
  const int wr = (wid >> 1) * 64;
  const int wc = (wid & 1) * 64;
  const int fr = lane & 15;
  const int fq = lane >> 4;
  const int srow = lane >> 2;
  const int schunk = lane & 3;

  f32x4 zero = {0.f, 0.f, 0.f, 0.f};
  f32x4 acc[4][4];
  for (int i = 0; i < 4; i++)
    for (int j = 0; j < 4; j++) acc[i][j] = zero;

  const int r0 = wid * 32;
  const u16* gA = A + (size_t)(m0 + r0 + srow) * 1024 + schunk * 8;
  const u16* gB = Bm + (size_t)(n0 + r0 + srow) * 1024 + schunk * 8;

  auto stage = [&](int buf, int k0) {
    u16* lA = &As[buf][r0 * 32];
    u16* lB = &Bs[buf][r0 * 32];
    __builtin_amdgcn_global_load_lds(
        (const __attribute__((address_space(1))) void*)(gA + k0),
        (__attribute__((address_space(3))) void*)(lA), 16, 0, 0);
    __builtin_amdgcn_global_load_lds(
        (const __attribute__((address_space(1))) void*)(gA + k0 + (size_t)16 * 1024),
        (__attribute__((address_space(3))) void*)(lA + 16 * 32), 16, 0, 0);
    __builtin_amdgcn_global_load_lds(
        (const __attribute__((address_space(1))) void*)(gB + k0),
        (__attribute__((address_space(3))) void*)(lB), 16, 0, 0);
    __builtin_amdgcn_global_load_lds(
        (const __attribute__((address_space(1))) void*)(gB + k0 + (size_t)16 * 1024),
        (__attribute__((address_space(3))) void*)(lB + 16 * 32), 16, 0, 0);
  };

  stage(0, kStart);
  stage(1, kStart + 32);
  asm volatile("s_waitcnt vmcnt(4)" ::: "memory");
  __builtin_amdgcn_s_barrier();

  for (int t = 0; t < NT; t++) {
    const int cur = t & 1;
    s16x8 af[4], bf[4];
#pragma unroll
    for (int mi = 0; mi < 4; mi++)
      af[mi] = *(const s16x8*)&As[cur][(wr + mi * 16 + fr) * 32 + fq * 8];
#pragma unroll
    for (int ni = 0; ni < 4; ni++)
      bf[ni] = *(const s16x8*)&Bs[cur][(wc + ni * 16 + fr) * 32 + fq * 8];
#pragma unroll
    for (int mi = 0; mi < 4; mi++)
#pragma unroll
      for (int ni = 0; ni < 4; ni++)
        acc[mi][ni] = __builtin_amdgcn_mfma_f32_16x16x32_bf16(af[mi], bf[ni],
                                                              acc[mi][ni], 0, 0, 0);
    __builtin_amdgcn_s_barrier();
    if (t + 2 < NT) {
      stage(cur, kStart + (t + 2) * 32);
      asm volatile("s_waitcnt vmcnt(4)" ::: "memory");
    } else {
      asm volatile("s_waitcnt vmcnt(0)" ::: "memory");
    }
    __builtin_amdgcn_s_barrier();
  }
#pragma unroll
  for (int mi = 0; mi < 4; mi++) {
#pragma unroll
    for (int ni = 0; ni < 4; ni++) {
      int row = m0 + wr + mi * 16 + fq * 4;
      int col = n0 + wc + ni * 16 + fr;
#pragma unroll
      for (int r = 0; r < 4; r++) C[(size_t)(row + r) * N + col] = acc[mi][ni][r];
    }
  }
}

// ---------- 256x256 KV GEMM, counted-vmcnt pipeline (T4), bf16 in/out, K=1024 ----------
#define BAR8 asm volatile("s_barrier" ::: "memory")
__global__ __launch_bounds__(512, 2) void gemm_bt256(const u16* __restrict__ A,
                                                     const u16* __restrict__ Bm,
                                                     u16* __restrict__ C) {
  __shared__ __align__(16) u16 lds[65536];
  const int N = 2048;
  const int tid = threadIdx.x;
  const int lane = tid & 63;
  const int w = tid >> 6;
  const int wr = w >> 2;
  const int wc = w & 3;
  const int fr = lane & 15;
  const int fq = lane >> 4;
  const int nwg = gridDim.x;
  const int cpx = nwg >> 3;
  const int bid = blockIdx.x;
  const int swz = (bid & 7) * cpx + (bid >> 3);
  const int nbn = N >> 8;
  const int bm = swz / nbn, bn = swz % nbn;
  const int gm0 = bm * 256, gn0 = bn * 256;
  const int NT = 16;

  f32x4 zero = {0.f, 0.f, 0.f, 0.f};
  f32x4 acc[8][4];
#pragma unroll
  for (int i = 0; i < 8; i++)
#pragma unroll
    for (int j = 0; j < 4; j++) acc[i][j] = zero;

  auto stage = [&](int buf, int t, int s) {
    int q = (s & 3) * 512 + tid;
    int row = q >> 3, p = q & 7;
    int l = p ^ (row & 7);
    const u16* src = (s < 4)
        ? A + (size_t)(gm0 + row) * 1024 + (t << 6) + l * 8
        : Bm + (size_t)(gn0 + row) * 1024 + (t << 6) + l * 8;
    u16* dst = &lds[buf * 32768 + ((s < 4) ? 0 : 16384) + ((s & 3) * 512 + w * 64) * 8];
    __builtin_amdgcn_global_load_lds(
        (const __attribute__((address_space(1))) void*)src,
        (__attribute__((address_space(3))) void*)dst, 16, 0, 0);
  };
  auto rdA = [&](int buf, int mi, int kk) -> s16x8 {
    int row = wr * 128 + mi * 16 + fr;
    int l = (kk * 4 + fq) ^ (fr & 7);
    return *(const s16x8*)&lds[buf * 32768 + row * 64 + l * 8];
  };
  auto rdB = [&](int buf, int ni, int kk) -> s16x8 {
    int row = wc * 64 + ni * 16 + fr;
    int l = (kk * 4 + fq) ^ (fr & 7);
    return *(const s16x8*)&lds[buf * 32768 + 16384 + row * 64 + l * 8];
  };

  s16x8 af[4][2], bf[4][2];

#pragma unroll
  for (int s = 4; s < 8; s++) stage(0, 0, s);
#pragma unroll
  for (int s = 0; s < 4; s++) stage(0, 0, s);
#pragma unroll
  for (int s = 4; s < 8; s++) stage(1, 1, s);
#pragma unroll
  for (int s = 0; s < 4; s++) stage(1, 1, s);
  asm volatile("s_waitcnt vmcnt(8)" ::: "memory");
  BAR8;

  for (int t = 0; t < NT; t++) {
    const int cur = t & 1;
    const bool st2 = (t + 2 < NT);
    // ---- P1
#pragma unroll
    for (int mi = 0; mi < 4; mi++)
#pragma unroll
      for (int kk = 0; kk < 2; kk++) af[mi][kk] = rdA(cur, mi, kk);
#pragma unroll
    for (int ni = 0; ni < 2; ni++)
#pragma unroll
      for (int kk = 0; kk < 2; kk++) bf[ni][kk] = rdB(cur, ni, kk);
    BAR8;
    __builtin_amdgcn_s_setprio(1);
#pragma unroll
    for (int mi = 0; mi < 4; mi++)
#pragma unroll
      for (int ni = 0; ni < 2; ni++)
#pragma unroll
        for (int kk = 0; kk < 2; kk++)
          acc[mi][ni] = __builtin_amdgcn_mfma_f32_16x16x32_bf16(af[mi][kk], bf[ni][kk],
                                                                acc[mi][ni], 0, 0, 0);
    __builtin_amdgcn_s_setprio(0);
    BAR8;
    // ---- P2
#pragma unroll
    for (int ni = 2; ni < 4; ni++)
#pragma unroll
      for (int kk = 0; kk < 2; kk++) bf[ni][kk] = rdB(cur, ni, kk);
    BAR8;
    __builtin_amdgcn_s_setprio(1);
#pragma unroll
    for (int mi = 0; mi < 4; mi++)
#pragma unroll
      for (int ni = 2; ni < 4; ni++)
#pragma unroll
        for (int kk = 0; kk < 2; kk++)
          acc[mi][ni] = __builtin_amdgcn_mfma_f32_16x16x32_bf16(af[mi][kk], bf[ni][kk],
                                                                acc[mi][ni], 0, 0, 0);
    __builtin_amdgcn_s_setprio(0);
    BAR8;
    // ---- P3
#pragma unroll
    for (int mi = 0; mi < 4; mi++)
#pragma unroll
      for (int kk = 0; kk < 2; kk++) af[mi][kk] = rdA(cur, mi + 4, kk);
    if (st2) {
#pragma unroll
      for (int s = 4; s < 8; s++) stage(cur, t + 2, s);
    }
    BAR8;
    __builtin_amdgcn_s_setprio(1);
#pragma unroll
    for (int mi = 0; mi < 4; mi++)
#pragma unroll
      for (int ni = 2; ni < 4; ni++)
#pragma unroll
        for (int kk = 0; kk < 2; kk++)
          acc[mi + 4][ni] = __builtin_amdgcn_mfma_f32_16x16x32_bf16(
              af[mi][kk], bf[ni][kk], acc[mi + 4][ni], 0, 0, 0);
    __builtin_amdgcn_s_setprio(0);
    BAR8;
    // ---- P4
    if (st2) {
#pragma unroll
      for (int s = 0; s < 4; s++) stage(cur, t + 2, s);
      asm volatile("s_waitcnt vmcnt(8)" ::: "memory");
    } else {
      asm volatile("s_waitcnt vmcnt(0)" ::: "memory");
    }
    BAR8;
    __builtin_amdgcn_s_setprio(1);
#pragma unroll
    for (int mi = 0; mi < 4; mi++)
#pragma unroll
      for (int ni = 0; ni < 2; ni++)
#pragma unroll
        for (int kk = 0; kk < 2; kk++)
          acc[mi + 4][ni] = __builtin_amdgcn_mfma_f32_16x16x32_bf16(
              af[mi][kk], bf[ni][kk], acc[mi + 4][ni], 0, 0, 0);
    __builtin_amdgcn_s_setprio(0);
    BAR8;
  }
#pragma unroll
  for (int mi = 0; mi < 8; mi++) {
#pragma unroll
    for (int ni = 0; ni < 4; ni++) {
      int row = gm0 + wr * 128 + mi * 16 + fq * 4;
      int col = gn0 + wc * 64 + ni * 16 + fr;
#pragma unroll
      for (int r = 0; r < 4; r++) C[(size_t)(row + r) * N + col] = f2bf(acc[mi][ni][r]);
    }
  }
}

// ---------- RMSNorm + RoPE for Q (sums 2 fp32 split-K partials) -> bf16 ----------
__global__ __launch_bounds__(256) void norm_rope_q(const float* __restrict__ src,
                                                   size_t partStride,
                                                   const float* __restrict__ w,
                                                   const int* __restrict__ pos,
                                                   u16* __restrict__ dst) {
  int wid = threadIdx.x >> 6;
  int lane = threadIdx.x & 63;
  int g = blockIdx.x * 4 + wid;
  int h = g & 15;
  int bl = g >> 4;
  int b = bl >> 10;
  int l = bl & 1023;
  size_t idx = (size_t)bl * 1024 + h * 64 + lane;
  float x = src[idx] + src[partStride + idx];
  float ss = x * x;
#pragma unroll
  for (int m = 1; m < 64; m <<= 1) ss += __shfl_xor(ss, m, 64);
  float xn = x * rsqrtf(ss * (1.0f / 64.0f) + 1e-6f) * w[lane];
  float p = __shfl_xor(xn, 32, 64);
  int j = lane & 31;
  float freq = exp2fast(-(float)j * (L2_10000 / 32.f));
  float ang = (float)pos[l] * freq;
  float c = cosf(ang), s = sinf(ang);
  float o = (lane < 32) ? (xn * c - p * s) : (p * s + xn * c);
  dst[((size_t)(b * 16 + h) * 1024 + l) * 64 + lane] = f2bf(o * QSCL);
}

// ---------- fused K-RMSNorm/RoPE + V-transpose (KVp bf16 -> Kb, Vt) ----------
__global__ __launch_bounds__(256) void normv_k(const u16* __restrict__ src,
                                               const float* __restrict__ w,
                                               const int* __restrict__ pos,
                                               u16* __restrict__ Kb,
                                               u16* __restrict__ Vt) {
  __shared__ u16 tile[64][66];
  int kt = blockIdx.x & 31;
  int bh = blockIdx.x >> 5;
  int h = bh & 15;
  int b = bh >> 4;
  int c = threadIdx.x & 63;
  int r4 = threadIdx.x >> 6;
  const u16* ksrc = src + ((size_t)(b * LK_ + kt * 64)) * 2048 + h * 128;
  u16* kdst = Kb + ((size_t)bh * LK_ + kt * 64) * 64;
  float wn = w[c];
  float freq = exp2fast(-(float)(c & 31) * (L2_10000 / 32.f));
#pragma unroll
  for (int p = 0; p < 16; p++) {
    int lk = p * 4 + r4;
    float x = bf2f(ksrc[(size_t)lk * 2048 + c]);
    float ss = x * x;
#pragma unroll
    for (int m = 1; m < 64; m <<= 1) ss += __shfl_xor(ss, m, 64);
    float xn = x * rsqrtf(ss * (1.0f / 64.0f) + 1e-6f) * wn;
    float pv = __shfl_xor(xn, 32, 64);
    float ang = (float)pos[kt * 64 + lk] * freq;
    float cc = cosf(ang), s = sinf(ang);
    float o = (c < 32) ? (xn * cc - pv * s) : (pv * s + xn * cc);
    kdst[(size_t)lk * 64 + c] = f2bf(o);
  }
  const u16* vsrc = ksrc + 64;
#pragma unroll
  for (int p = 0; p < 16; p++) {
    int lk = p * 4 + r4;
    tile[lk][c] = vsrc[(size_t)lk * 2048 + c];
  }
  __syncthreads();
  u16* vdst = Vt + (size_t)bh * 64 * LK_ + kt * 64;
#pragma unroll
  for (int p = 0; p < 16; p++) {
    int dh = p * 4 + r4;
    vdst[(size_t)dh * LK_ + c] = tile[c][dh];
  }
}

// ---------- sum of 2 split-K partials -> out ----------
__global__ __launch_bounds__(256) void reduce2_k(const float* __restrict__ p,
                                                 float* __restrict__ out, int n) {
  int i = (blockIdx.x * 256 + threadIdx.x) * 4;
  if (i >= n) return;
  float4 a = *(const float4*)(p + i);
  float4 b = *(const float4*)(p + (size_t)n + i);
  float4 r = make_float4(a.x + b.x, a.y + b.y, a.z + b.z, a.w + b.w);
  *(float4*)(out + i) = r;
}

// ---------- flash attention v8: unrolled x2 (no state copies) + ones-denominator ----------
__global__ __launch_bounds__(256) void flash_k(const u16* __restrict__ qb,
                                               const u16* __restrict__ kb,
                                               const u16* __restrict__ vb,
                                               u16* __restrict__ y1) {
  __shared__ __align__(16) u16 Ks[2][64][64];
  __shared__ __align__(16) u16 Vs[2][64][64];
  const int tid = threadIdx.x;
  const int lane = tid & 63;
  const int wid = tid >> 6;
  const int fr = lane & 15;
  const int fq = lane >> 4;
  int bid = blockIdx.x;
  int vbid = (bid & 7) * 64 + (bid >> 3);
  int qt = vbid & 7;
  int bh = vbid >> 3;
  const u16* qbase = qb + ((size_t)bh * LQ_ + qt * 128 + wid * 32) * 64;
  const u16* kbase = kb + (size_t)bh * LK_ * 64;
  const u16* vbase = vb + (size_t)bh * 64 * LK_;
  s16x8 qf0a = *(const s16x8*)(qbase + (size_t)fr * 64 + fq * 8);
  s16x8 qf1a = *(const s16x8*)(qbase + (size_t)fr * 64 + 32 + fq * 8);
  s16x8 qf0b = *(const s16x8*)(qbase + (size_t)(16 + fr) * 64 + fq * 8);
  s16x8 qf1b = *(const s16x8*)(qbase + (size_t)(16 + fr) * 64 + 32 + fq * 8);
  s16x8 ones;
#pragma unroll
  for (int e = 0; e < 8; e++) ones[e] = (short)0x3F80;
  float mrunA = -1e30f, mrunB = -1e30f;
  f32x4 zero = {0.f, 0.f, 0.f, 0.f};
  f32x4 yaccA[4], yaccB[4], yonesA = zero, yonesB = zero;
#pragma unroll
  for (int ni = 0; ni < 4; ni++) { yaccA[ni] = zero; yaccB[ni] = zero; }
  const int srow = tid >> 3;
  const int schunk = tid & 7;
  const int c2 = schunk >> 2, c1 = (schunk >> 1) & 1, c0 = schunk & 1;
  const int vg1 = 4 * c2 + 2 * c0;
  const int voff = 4 * c1;
  // loop-invariant swizzled read offsets (bytes/2 = u16 index)
  const int kread0 = (fq ^ (fr & 7)) << 3;
  const int kread1 = ((4 + fq) ^ (fr & 7)) << 3;
  const int vread0 = ((fq) ^ (fr & 7)) << 3;        // s2 = 0
  const int vread1 = ((4 + fq) ^ (fr & 7)) << 3;    // s2 = 1

  auto kaddr = [&](int bufi, int row) -> u16* {
    return &Ks[bufi][row][(schunk ^ (row & 7)) << 3];
  };
  auto stageV = [&](int bufi, int row, u16x8 v) {
    u16x4 lo4 = __builtin_shufflevector(v, v, 0, 1, 2, 3);
    u16x4 hi4 = __builtin_shufflevector(v, v, 4, 5, 6, 7);
    *(u16x4*)&Vs[bufi][row][((vg1 ^ (row & 7)) << 3) + voff] = lo4;
    *(u16x4*)&Vs[bufi][row][(((vg1 + 1) ^ (row & 7)) << 3) + voff] = hi4;
  };
  auto qk2 = [&](int bufi, f32x4 (&sA)[4], f32x4 (&sB)[4]) {
#pragma unroll
    for (int ni = 0; ni < 4; ni++) { sA[ni] = zero; sB[ni] = zero; }
#pragma unroll
    for (int ni = 0; ni < 4; ni++) {
      int row = ni * 16 + fr;
      s16x8 kf0 = *(const s16x8*)&Ks[bufi][row][kread0];
      s16x8 kf1 = *(const s16x8*)&Ks[bufi][row][kread1];
      sA[ni] = __builtin_amdgcn_mfma_f32_16x16x32_bf16(kf0, qf0a, sA[ni], 0, 0, 0);
      sA[ni] = __builtin_amdgcn_mfma_f32_16x16x32_bf16(kf1, qf1a, sA[ni], 0, 0, 0);
      sB[ni] = __builtin_amdgcn_mfma_f32_16x16x32_bf16(kf0, qf0b, sB[ni], 0, 0, 0);
      sB[ni] = __builtin_amdgcn_mfma_f32_16x16x32_bf16(kf1, qf1b, sB[ni], 0, 0, 0);
    }
  };
  auto softmax = [&](f32x4 (&sp)[4], float& mrun, f32x4 (&yacc)[4], f32x4& yones) {
    float m0 = fmaxf(fmaxf(sp[0][0], sp[0][1]), sp[0][2]);
    float m1 = fmaxf(fmaxf(sp[0][3], sp[1][0]), sp[1][1]);
    float m2 = fmaxf(fmaxf(sp[1][2], sp[1][3]), sp[2][0]);
    float m3 = fmaxf(fmaxf(sp[2][1], sp[2][2]), sp[2][3]);
    float m4 = fmaxf(fmaxf(sp[3][0], sp[3][1]), sp[3][2]);
    float mx = fmaxf(fmaxf(fmaxf(m0, m1), m2), fmaxf(fmaxf(m3, m4), sp[3][3]));
    mx = fmaxf(mx, __shfl_xor(mx, 16, 64));
    mx = fmaxf(mx, __shfl_xor(mx, 32, 64));
    bool skip = __all(mx <= mrun + 10.0f);
    if (!skip) {
      float mn = fmaxf(mrun, mx);
      float alpha = exp2fast(mrun - mn);
      mrun = mn;
      float va[4];
#pragma unroll
      for (int r = 0; r < 4; r++) va[r] = __shfl(alpha, fq * 4 + r, 64);
#pragma unroll
      for (int ni = 0; ni < 4; ni++)
#pragma unroll
        for (int r = 0; r < 4; r++) yacc[ni][r] *= va[r];
#pragma unroll
      for (int r = 0; r < 4; r++) yones[r] *= va[r];
    }
#pragma unroll
    for (int ni = 0; ni < 4; ni++)
#pragma unroll
      for (int r = 0; r < 4; r++) sp[ni][r] = exp2fast(sp[ni][r] - mrun);
  };
  auto pv = [&](int bufi, f32x4 (&sA)[4], f32x4 (&sB)[4]) {
#pragma unroll
    for (int s2 = 0; s2 < 2; s2++) {
      int vrd = s2 ? vread1 : vread0;
      union { uint32_t u[4]; s16x8 v8; } puA, puB;
      puA.u[0] = cvtpk(sA[2 * s2][0], sA[2 * s2][1]);
      puA.u[1] = cvtpk(sA[2 * s2][2], sA[2 * s2][3]);
      puA.u[2] = cvtpk(sA[2 * s2 + 1][0], sA[2 * s2 + 1][1]);
      puA.u[3] = cvtpk(sA[2 * s2 + 1][2], sA[2 * s2 + 1][3]);
      puB.u[0] = cvtpk(sB[2 * s2][0], sB[2 * s2][1]);
      puB.u[1] = cvtpk(sB[2 * s2][2], sB[2 * s2][3]);
      puB.u[2] = cvtpk(sB[2 * s2 + 1][0], sB[2 * s2 + 1][1]);
      puB.u[3] = cvtpk(sB[2 * s2 + 1][2], sB[2 * s2 + 1][3]);
#pragma unroll
      for (int ni = 0; ni < 4; ni++) {
        int row = ni * 16 + fr;
        s16x8 vf = *(const s16x8*)&Vs[bufi][row][vrd];
        yaccA[ni] = __builtin_amdgcn_mfma_f32_16x16x32_bf16(puA.v8, vf, yaccA[ni], 0, 0, 0);
        yaccB[ni] = __builtin_amdgcn_mfma_f32_16x16x32_bf16(puB.v8, vf, yaccB[ni], 0, 0, 0);
      }
      yonesA = __builtin_amdgcn_mfma_f32_16x16x32_bf16(puA.v8, ones, yonesA, 0, 0, 0);
      yonesB = __builtin_amdgcn_mfma_f32_16x16x32_bf16(puB.v8, ones, yonesB, 0, 0, 0);
    }
  };
  auto stageTile = [&](int bufi, int kt) {
    u16x8 k0 = *(const u16x8*)(kbase + (size_t)(kt + srow) * 64 + schunk * 8);
    u16x8 k1 = *(const u16x8*)(kbase + (size_t)(kt + srow + 32) * 64 + schunk * 8);
    u16x8 v0 = *(const u16x8*)(vbase + (size_t)srow * LK_ + kt + schunk * 8);
    u16x8 v1 = *(const u16x8*)(vbase + (size_t)(srow + 32) * LK_ + kt + schunk * 8);
    *(u16x8*)kaddr(bufi, srow) = k0;
    *(u16x8*)kaddr(bufi, srow + 32) = k1;
    stageV(bufi, srow, v0);
    stageV(bufi, srow + 32, v1);
  };

  const int NT = LK_ / 64;  // 32, even
  f32x4 spA[4], spB[4], snA[4], snB[4];

  // prologue
  stageTile(0, 0);
  __syncthreads();
  stageTile(1, 64);
  qk2(0, spA, spB);  // reads Ks[0] only
  __syncthreads();

  for (int t = 0; t < NT; t += 2) {
    // ---- sub-iter 0: tile t (buf 0); current sp*, next -> sn*
    {
      const bool st2 = (t + 2 < NT);
      u16x8 kr0, kr1, vr0, vr1;
      if (st2) {
        int kt = (t + 2) * 64;
        kr0 = *(const u16x8*)(kbase + (size_t)(kt + srow) * 64 + schunk * 8);
        kr1 = *(const u16x8*)(kbase + (size_t)(kt + srow + 32) * 64 + schunk * 8);
        vr0 = *(const u16x8*)(vbase + (size_t)srow * LK_ + kt + schunk * 8);
        vr1 = *(const u16x8*)(vbase + (size_t)(srow + 32) * LK_ + kt + schunk * 8);
      }
      qk2(1, snA, snB);  // t+1 scores (t+1 < NT always; NT even)
      softmax(spA, mrunA, yaccA, yonesA);
      softmax(spB, mrunB, yaccB, yonesB);
      pv(0, spA, spB);
      __syncthreads();
      if (st2) {
        *(u16x8*)kaddr(0, srow) = kr0;
        *(u16x8*)kaddr(0, srow + 32) = kr1;
        stageV(0, srow, vr0);
        stageV(0, srow + 32, vr1);
      }
      __syncthreads();
    }
    // ---- sub-iter 1: tile t+1 (buf 1); current sn*, next -> sp*
    {
      const bool st3 = (t + 3 < NT);
      u16x8 kr0, kr1, vr0, vr1;
      if (st3) {
        int kt = (t + 3) * 64;
        kr0 = *(const u16x8*)(kbase + (size_t)(kt + srow) * 64 + schunk * 8);
        kr1 = *(const u16x8*)(kbase + (size_t)(kt + srow + 32) * 64 + schunk * 8);
        vr0 = *(const u16x8*)(vbase + (size_t)srow * LK_ + kt + schunk * 8);
        vr1 = *(const u16x8*)(vbase + (size_t)(srow + 32) * LK_ + kt + schunk * 8);
      }
      if (t + 2 < NT) qk2(0, spA, spB);  // t+2 scores from freshly-written buf 0
      softmax(snA, mrunA, yaccA, yonesA);
      softmax(snB, mrunB, yaccB, yonesB);
      pv(1, snA, snB);
      __syncthreads();
      if (st3) {
        *(u16x8*)kaddr(1, srow) = kr0;
        *(u16x8*)kaddr(1, srow + 32) = kr1;
        stageV(1, srow, vr0);
        stageV(1, srow + 32, vr1);
      }
      __syncthreads();
    }
  }
  int b = bh >> 4, h = bh & 15;
  u16* yoA = y1 + ((size_t)(b * LQ_ + qt * 128 + wid * 32 + fq * 4)) * 1024 + h * 64;
  u16* yoB = yoA + (size_t)16 * 1024;
#pragma unroll
  for (int ni = 0; ni < 4; ni++) {
#pragma unroll
    for (int r = 0; r < 4; r++) {
      yoA[(size_t)r * 1024 + ni * 16 + fr] = f2bf(yaccA[ni][r] / yonesA[r]);
      yoB[(size_t)r * 1024 + ni * 16 + fr] = f2bf(yaccB[ni][r] / yonesB[r]);
    }
  }
}

extern "C" void kernel_launch(void* const* d_in, const int* in_sizes, int n_in,
                              void* d_out, int out_size, void* d_ws, size_t ws_size,
                              hipStream_t stream) {
  (void)in_sizes; (void)n_in; (void)out_size;
  const float* queries = (const float*)d_in[0];
  const float* kv = (const float*)d_in[1];
  const float* wq = (const float*)d_in[2];
  const float* wkv = (const float*)d_in[3];
  const float* wo = (const float*)d_in[4];
  const float* qnw = (const float*)d_in[5];
  const float* knw = (const float*)d_in[6];
  const int* pos_q = (const int*)d_in[7];
  const int* pos_k = (const int*)d_in[8];
  float* out = (float*)d_out;

  char* ws = (char*)d_ws;
  size_t off = 0;
  auto alloc = [&](size_t sz) { void* p = ws + off; off += sz; return p; };
  u16* Aq1 = (u16*)alloc((size_t)4096 * 1024 * 2);
  u16* Wqh = (u16*)alloc((size_t)1024 * 1024 * 2);
  u16* Akv1 = (u16*)alloc((size_t)8192 * 1024 * 2);
  u16* Wkvh = (u16*)alloc((size_t)2048 * 1024 * 2);
  u16* Woh = (u16*)alloc((size_t)1024 * 1024 * 2);
  u16* KVp = (u16*)alloc((size_t)8192 * 2048 * 2);
  u16* Qb = (u16*)alloc((size_t)64 * 1024 * 64 * 2);
  u16* Kb = (u16*)alloc((size_t)64 * 2048 * 64 * 2);
  u16* Vt = (u16*)alloc((size_t)64 * 2048 * 64 * 2);
  u16* Y1 = (u16*)alloc((size_t)4096 * 1024 * 2);
  float* Part = (float*)alloc((size_t)2 * 4096 * 1024 * 4);
  if (off > ws_size) return;

  const size_t PSTRIDE = (size_t)4096 * 1024;

  // all 5 input casts in one launch
  cast5_k<<<16384, 256, 0, stream>>>(queries, Aq1, wq, Wqh, kv, Akv1, wkv, Wkvh, wo, Woh);
  // KV projection -> KVp bf16 (K=1024)
  gemm_bt256<<<(8192 / 256) * (2048 / 256), 512, 0, stream>>>(Akv1, Wkvh, KVp);
  // Q projection split-K=2 -> Part
  gemm_bt<<<dim3(4096 / 128, 1024 / 128, 2), 256, 0, stream>>>(Aq1, Wqh, Part, 1024);
  norm_rope_q<<<4096 * 16 / 4, 256, 0, stream>>>(Part, PSTRIDE, qnw, pos_q, Qb);
  // fused K-norm/rope + V-transpose
  normv_k<<<64 * 32, 256, 0, stream>>>(KVp, knw, pos_k, Kb, Vt);
  flash_k<<<64 * 8, 256, 0, stream>>>(Qb, Kb, Vt, Y1);
  // O projection split-K=2 + reduce -> out
  gemm_bt<<<dim3(4096 / 128, 1024 / 128, 2), 256, 0, stream>>>(Y1, Woh, Part, 1024);
  reduce2_k<<<4096, 256, 0, stream>>>(Part, out, 4096 * 1024);
}

// Round 18
// 192.625 us; speedup vs baseline: 1.1018x; 1.1018x over previous
//
#include <hip/hip_runtime.h>
#include <stdint.h>

typedef unsigned short u16;
typedef u16 u16x8 __attribute__((ext_vector_type(8)));
typedef u16 u16x4 __attribute__((ext_vector_type(4)));
typedef short s16x8 __attribute__((ext_vector_type(8)));
typedef float f32x4 __attribute__((ext_vector_type(4)));

#define B_ 4
#define LQ_ 1024
#define LK_ 2048
#define D_ 1024
#define H_ 16
#define DH_ 64
#define QSCL 0.1803368801111204f
#define L2_10000 13.287712379549449f

__device__ __forceinline__ u16 f2bf(float x) {
  uint32_t u = __float_as_uint(x);
  u += 0x7FFFu + ((u >> 16) & 1u);
  return (u16)(u >> 16);
}
__device__ __forceinline__ float bf2f(u16 h) {
  return __uint_as_float(((uint32_t)h) << 16);
}
__device__ __forceinline__ uint32_t cvtpk(float lo, float hi) {
  uint32_t r;
  asm("v_cvt_pk_bf16_f32 %0, %1, %2" : "=v"(r) : "v"(lo), "v"(hi));
  return r;
}
__device__ __forceinline__ float exp2fast(float x) {
  float r;
  asm("v_exp_f32 %0, %1" : "=v"(r) : "v"(x));
  return r;
}

// ---------- merged fp32->bf16 casts for all 5 inputs (one launch) ----------
__global__ __launch_bounds__(256) void cast5_k(const float* __restrict__ s0, u16* __restrict__ d0,
                                               const float* __restrict__ s1, u16* __restrict__ d1,
                                               const float* __restrict__ s2, u16* __restrict__ d2,
                                               const float* __restrict__ s3, u16* __restrict__ d3,
                                               const float* __restrict__ s4, u16* __restrict__ d4) {
  int b = blockIdx.x;
  const float* s;
  u16* d;
  int base;
  if (b < 4096) { s = s0; d = d0; base = b; }
  else if (b < 5120) { s = s1; d = d1; base = b - 4096; }
  else if (b < 13312) { s = s2; d = d2; base = b - 5120; }
  else if (b < 15360) { s = s3; d = d3; base = b - 13312; }
  else { s = s4; d = d4; base = b - 15360; }
  int i = (base * 256 + threadIdx.x) * 4;
  float4 v = *(const float4*)(s + i);
  ushort4 o;
  o.x = f2bf(v.x); o.y = f2bf(v.y); o.z = f2bf(v.z); o.w = f2bf(v.w);
  *(ushort4*)(d + i) = o;
}

// ---------- 128x128 GEMM, split-K (Q/O), T4 counted-vmcnt double-buffer ----------
__global__ __launch_bounds__(256) void gemm_bt(const u16* __restrict__ A,
                                               const u16* __restrict__ Bm,
                                               float* __restrict__ C,
                                               int N) {
  __shared__ __align__(16) u16 As[2][128 * 32];
  __shared__ __align__(16) u16 Bs[2][128 * 32];
  const int tid = threadIdx.x;
  const int lane = tid & 63;
  const int wid = tid >> 6;
  const int m0 = blockIdx.x * 128;
  const int n0 = blockIdx.y * 128;
  const int slice = 1024 / gridDim.z;
  const int kStart = blockIdx.z * slice;
  const int NT = slice >> 5;
  C += (size_t)blockIdx.z * (size_t)gridDim.x * 128 * N;
  const int wr = (wid >> 1) * 64;
  const int wc = (wid & 1) * 64;
  const int fr = lane & 15;
  const int fq = lane >> 4;
  const int srow = lane >> 2;
  const int schunk = lane & 3;

  f32x4 zero = {0.f, 0.f, 0.f, 0.f};
  f32x4 acc[4][4];
  for (int i = 0; i < 4; i++)
    for (int j = 0; j < 4; j++) acc[i][j] = zero;

  const int r0 = wid * 32;
  const u16* gA = A + (size_t)(m0 + r0 + srow) * 1024 + schunk * 8;
  const u16* gB = Bm + (size_t)(n0 + r0 + srow) * 1024 + schunk * 8;

  auto stage = [&](int buf, int k0) {
    u16* lA = &As[buf][r0 * 32];
    u16* lB = &Bs[buf][r0 * 32];
    __builtin_amdgcn_global_load_lds(
        (const __attribute__((address_space(1))) void*)(gA + k0),
        (__attribute__((address_space(3))) void*)(lA), 16, 0, 0);
    __builtin_amdgcn_global_load_lds(
        (const __attribute__((address_space(1))) void*)(gA + k0 + (size_t)16 * 1024),
        (__attribute__((address_space(3))) void*)(lA + 16 * 32), 16, 0, 0);
    __builtin_amdgcn_global_load_lds(
        (const __attribute__((address_space(1))) void*)(gB + k0),
        (__attribute__((address_space(3))) void*)(lB), 16, 0, 0);
    __builtin_amdgcn_global_load_lds(
        (const __attribute__((address_space(1))) void*)(gB + k0 + (size_t)16 * 1024),
        (__attribute__((address_space(3))) void*)(lB + 16 * 32), 16, 0, 0);
  };

  stage(0, kStart);
  stage(1, kStart + 32);
  asm volatile("s_waitcnt vmcnt(4)" ::: "memory");
  __builtin_amdgcn_s_barrier();

  for (int t = 0; t < NT; t++) {
    const int cur = t & 1;
    s16x8 af[4], bf[4];
#pragma unroll
    for (int mi = 0; mi < 4; mi++)
      af[mi] = *(const s16x8*)&As[cur][(wr + mi * 16 + fr) * 32 + fq * 8];
#pragma unroll
    for (int ni = 0; ni < 4; ni++)
      bf[ni] = *(const s16x8*)&Bs[cur][(wc + ni * 16 + fr) * 32 + fq * 8];
#pragma unroll
    for (int mi = 0; mi < 4; mi++)
#pragma unroll
      for (int ni = 0; ni < 4; ni++)
        acc[mi][ni] = __builtin_amdgcn_mfma_f32_16x16x32_bf16(af[mi], bf[ni],
                                                              acc[mi][ni], 0, 0, 0);
    __builtin_amdgcn_s_barrier();
    if (t + 2 < NT) {
      stage(cur, kStart + (t + 2) * 32);
      asm volatile("s_waitcnt vmcnt(4)" ::: "memory");
    } else {
      asm volatile("s_waitcnt vmcnt(0)" ::: "memory");
    }
    __builtin_amdgcn_s_barrier();
  }
#pragma unroll
  for (int mi = 0; mi < 4; mi++) {
#pragma unroll
    for (int ni = 0; ni < 4; ni++) {
      int row = m0 + wr + mi * 16 + fq * 4;
      int col = n0 + wc + ni * 16 + fr;
#pragma unroll
      for (int r = 0; r < 4; r++) C[(size_t)(row + r) * N + col] = acc[mi][ni][r];
    }
  }
}

// ---------- 256x256 KV GEMM, counted-vmcnt pipeline (T4), bf16 in/out, K=1024 ----------
#define BAR8 asm volatile("s_barrier" ::: "memory")
__global__ __launch_bounds__(512, 2) void gemm_bt256(const u16* __restrict__ A,
                                                     const u16* __restrict__ Bm,
                                                     u16* __restrict__ C) {
  __shared__ __align__(16) u16 lds[65536];
  const int N = 2048;
  const int tid = threadIdx.x;
  const int lane = tid & 63;
  const int w = tid >> 6;
  const int wr = w >> 2;
  const int wc = w & 3;
  const int fr = lane & 15;
  const int fq = lane >> 4;
  const int nwg = gridDim.x;
  const int cpx = nwg >> 3;
  const int bid = blockIdx.x;
  const int swz = (bid & 7) * cpx + (bid >> 3);
  const int nbn = N >> 8;
  const int bm = swz / nbn, bn = swz % nbn;
  const int gm0 = bm * 256, gn0 = bn * 256;
  const int NT = 16;

  f32x4 zero = {0.f, 0.f, 0.f, 0.f};
  f32x4 acc[8][4];
#pragma unroll
  for (int i = 0; i < 8; i++)
#pragma unroll
    for (int j = 0; j < 4; j++) acc[i][j] = zero;

  auto stage = [&](int buf, int t, int s) {
    int q = (s & 3) * 512 + tid;
    int row = q >> 3, p = q & 7;
    int l = p ^ (row & 7);
    const u16* src = (s < 4)
        ? A + (size_t)(gm0 + row) * 1024 + (t << 6) + l * 8
        : Bm + (size_t)(gn0 + row) * 1024 + (t << 6) + l * 8;
    u16* dst = &lds[buf * 32768 + ((s < 4) ? 0 : 16384) + ((s & 3) * 512 + w * 64) * 8];
    __builtin_amdgcn_global_load_lds(
        (const __attribute__((address_space(1))) void*)src,
        (__attribute__((address_space(3))) void*)dst, 16, 0, 0);
  };
  auto rdA = [&](int buf, int mi, int kk) -> s16x8 {
    int row = wr * 128 + mi * 16 + fr;
    int l = (kk * 4 + fq) ^ (fr & 7);
    return *(const s16x8*)&lds[buf * 32768 + row * 64 + l * 8];
  };
  auto rdB = [&](int buf, int ni, int kk) -> s16x8 {
    int row = wc * 64 + ni * 16 + fr;
    int l = (kk * 4 + fq) ^ (fr & 7);
    return *(const s16x8*)&lds[buf * 32768 + 16384 + row * 64 + l * 8];
  };

  s16x8 af[4][2], bf[4][2];

#pragma unroll
  for (int s = 4; s < 8; s++) stage(0, 0, s);
#pragma unroll
  for (int s = 0; s < 4; s++) stage(0, 0, s);
#pragma unroll
  for (int s = 4; s < 8; s++) stage(1, 1, s);
#pragma unroll
  for (int s = 0; s < 4; s++) stage(1, 1, s);
  asm volatile("s_waitcnt vmcnt(8)" ::: "memory");
  BAR8;

  for (int t = 0; t < NT; t++) {
    const int cur = t & 1;
    const bool st2 = (t + 2 < NT);
    // ---- P1
#pragma unroll
    for (int mi = 0; mi < 4; mi++)
#pragma unroll
      for (int kk = 0; kk < 2; kk++) af[mi][kk] = rdA(cur, mi, kk);
#pragma unroll
    for (int ni = 0; ni < 2; ni++)
#pragma unroll
      for (int kk = 0; kk < 2; kk++) bf[ni][kk] = rdB(cur, ni, kk);
    BAR8;
    __builtin_amdgcn_s_setprio(1);
#pragma unroll
    for (int mi = 0; mi < 4; mi++)
#pragma unroll
      for (int ni = 0; ni < 2; ni++)
#pragma unroll
        for (int kk = 0; kk < 2; kk++)
          acc[mi][ni] = __builtin_amdgcn_mfma_f32_16x16x32_bf16(af[mi][kk], bf[ni][kk],
                                                                acc[mi][ni], 0, 0, 0);
    __builtin_amdgcn_s_setprio(0);
    BAR8;
    // ---- P2
#pragma unroll
    for (int ni = 2; ni < 4; ni++)
#pragma unroll
      for (int kk = 0; kk < 2; kk++) bf[ni][kk] = rdB(cur, ni, kk);
    BAR8;
    __builtin_amdgcn_s_setprio(1);
#pragma unroll
    for (int mi = 0; mi < 4; mi++)
#pragma unroll
      for (int ni = 2; ni < 4; ni++)
#pragma unroll
        for (int kk = 0; kk < 2; kk++)
          acc[mi][ni] = __builtin_amdgcn_mfma_f32_16x16x32_bf16(af[mi][kk], bf[ni][kk],
                                                                acc[mi][ni], 0, 0, 0);
    __builtin_amdgcn_s_setprio(0);
    BAR8;
    // ---- P3
#pragma unroll
    for (int mi = 0; mi < 4; mi++)
#pragma unroll
      for (int kk = 0; kk < 2; kk++) af[mi][kk] = rdA(cur, mi + 4, kk);
    if (st2) {
#pragma unroll
      for (int s = 4; s < 8; s++) stage(cur, t + 2, s);
    }
    BAR8;
    __builtin_amdgcn_s_setprio(1);
#pragma unroll
    for (int mi = 0; mi < 4; mi++)
#pragma unroll
      for (int ni = 2; ni < 4; ni++)
#pragma unroll
        for (int kk = 0; kk < 2; kk++)
          acc[mi + 4][ni] = __builtin_amdgcn_mfma_f32_16x16x32_bf16(
              af[mi][kk], bf[ni][kk], acc[mi + 4][ni], 0, 0, 0);
    __builtin_amdgcn_s_setprio(0);
    BAR8;
    // ---- P4
    if (st2) {
#pragma unroll
      for (int s = 0; s < 4; s++) stage(cur, t + 2, s);
      asm volatile("s_waitcnt vmcnt(8)" ::: "memory");
    } else {
      asm volatile("s_waitcnt vmcnt(0)" ::: "memory");
    }
    BAR8;
    __builtin_amdgcn_s_setprio(1);
#pragma unroll
    for (int mi = 0; mi < 4; mi++)
#pragma unroll
      for (int ni = 0; ni < 2; ni++)
#pragma unroll
        for (int kk = 0; kk < 2; kk++)
          acc[mi + 4][ni] = __builtin_amdgcn_mfma_f32_16x16x32_bf16(
              af[mi][kk], bf[ni][kk], acc[mi + 4][ni], 0, 0, 0);
    __builtin_amdgcn_s_setprio(0);
    BAR8;
  }
#pragma unroll
  for (int mi = 0; mi < 8; mi++) {
#pragma unroll
    for (int ni = 0; ni < 4; ni++) {
      int row = gm0 + wr * 128 + mi * 16 + fq * 4;
      int col = gn0 + wc * 64 + ni * 16 + fr;
#pragma unroll
      for (int r = 0; r < 4; r++) C[(size_t)(row + r) * N + col] = f2bf(acc[mi][ni][r]);
    }
  }
}

// ---------- RMSNorm + RoPE for Q (sums 2 fp32 split-K partials) -> bf16 ----------
__global__ __launch_bounds__(256) void norm_rope_q(const float* __restrict__ src,
                                                   size_t partStride,
                                                   const float* __restrict__ w,
                                                   const int* __restrict__ pos,
                                                   u16* __restrict__ dst) {
  int wid = threadIdx.x >> 6;
  int lane = threadIdx.x & 63;
  int g = blockIdx.x * 4 + wid;
  int h = g & 15;
  int bl = g >> 4;
  int b = bl >> 10;
  int l = bl & 1023;
  size_t idx = (size_t)bl * 1024 + h * 64 + lane;
  float x = src[idx] + src[partStride + idx];
  float ss = x * x;
#pragma unroll
  for (int m = 1; m < 64; m <<= 1) ss += __shfl_xor(ss, m, 64);
  float xn = x * rsqrtf(ss * (1.0f / 64.0f) + 1e-6f) * w[lane];
  float p = __shfl_xor(xn, 32, 64);
  int j = lane & 31;
  float freq = exp2fast(-(float)j * (L2_10000 / 32.f));
  float ang = (float)pos[l] * freq;
  float c = cosf(ang), s = sinf(ang);
  float o = (lane < 32) ? (xn * c - p * s) : (p * s + xn * c);
  dst[((size_t)(b * 16 + h) * 1024 + l) * 64 + lane] = f2bf(o * QSCL);
}

// ---------- fused K-RMSNorm/RoPE + V-transpose (KVp bf16 -> Kb, Vt) ----------
__global__ __launch_bounds__(256) void normv_k(const u16* __restrict__ src,
                                               const float* __restrict__ w,
                                               const int* __restrict__ pos,
                                               u16* __restrict__ Kb,
                                               u16* __restrict__ Vt) {
  __shared__ u16 tile[64][66];
  int kt = blockIdx.x & 31;
  int bh = blockIdx.x >> 5;
  int h = bh & 15;
  int b = bh >> 4;
  int c = threadIdx.x & 63;
  int r4 = threadIdx.x >> 6;
  const u16* ksrc = src + ((size_t)(b * LK_ + kt * 64)) * 2048 + h * 128;
  u16* kdst = Kb + ((size_t)bh * LK_ + kt * 64) * 64;
  float wn = w[c];
  float freq = exp2fast(-(float)(c & 31) * (L2_10000 / 32.f));
#pragma unroll
  for (int p = 0; p < 16; p++) {
    int lk = p * 4 + r4;
    float x = bf2f(ksrc[(size_t)lk * 2048 + c]);
    float ss = x * x;
#pragma unroll
    for (int m = 1; m < 64; m <<= 1) ss += __shfl_xor(ss, m, 64);
    float xn = x * rsqrtf(ss * (1.0f / 64.0f) + 1e-6f) * wn;
    float pv = __shfl_xor(xn, 32, 64);
    float ang = (float)pos[kt * 64 + lk] * freq;
    float cc = cosf(ang), s = sinf(ang);
    float o = (c < 32) ? (xn * cc - pv * s) : (pv * s + xn * cc);
    kdst[(size_t)lk * 64 + c] = f2bf(o);
  }
  const u16* vsrc = ksrc + 64;
#pragma unroll
  for (int p = 0; p < 16; p++) {
    int lk = p * 4 + r4;
    tile[lk][c] = vsrc[(size_t)lk * 2048 + c];
  }
  __syncthreads();
  u16* vdst = Vt + (size_t)bh * 64 * LK_ + kt * 64;
#pragma unroll
  for (int p = 0; p < 16; p++) {
    int dh = p * 4 + r4;
    vdst[(size_t)dh * LK_ + c] = tile[c][dh];
  }
}

// ---------- sum of 2 split-K partials -> out ----------
__global__ __launch_bounds__(256) void reduce2_k(const float* __restrict__ p,
                                                 float* __restrict__ out, int n) {
  int i = (blockIdx.x * 256 + threadIdx.x) * 4;
  if (i >= n) return;
  float4 a = *(const float4*)(p + i);
  float4 b = *(const float4*)(p + (size_t)n + i);
  float4 r = make_float4(a.x + b.x, a.y + b.y, a.z + b.z, a.w + b.w);
  *(float4*)(out + i) = r;
}

// ---------- flash attention v7 (r16-verified): ones-denominator + Q-block + T15 ----------
__global__ __launch_bounds__(256) void flash_k(const u16* __restrict__ qb,
                                               const u16* __restrict__ kb,
                                               const u16* __restrict__ vb,
                                               u16* __restrict__ y1) {
  __shared__ __align__(16) u16 Ks[2][64][64];
  __shared__ __align__(16) u16 Vs[2][64][64];
  const int tid = threadIdx.x;
  const int lane = tid & 63;
  const int wid = tid >> 6;
  const int fr = lane & 15;
  const int fq = lane >> 4;
  int bid = blockIdx.x;
  int vbid = (bid & 7) * 64 + (bid >> 3);
  int qt = vbid & 7;
  int bh = vbid >> 3;
  const u16* qbase = qb + ((size_t)bh * LQ_ + qt * 128 + wid * 32) * 64;
  const u16* kbase = kb + (size_t)bh * LK_ * 64;
  const u16* vbase = vb + (size_t)bh * 64 * LK_;
  s16x8 qf0a = *(const s16x8*)(qbase + (size_t)fr * 64 + fq * 8);
  s16x8 qf1a = *(const s16x8*)(qbase + (size_t)fr * 64 + 32 + fq * 8);
  s16x8 qf0b = *(const s16x8*)(qbase + (size_t)(16 + fr) * 64 + fq * 8);
  s16x8 qf1b = *(const s16x8*)(qbase + (size_t)(16 + fr) * 64 + 32 + fq * 8);
  s16x8 ones;
#pragma unroll
  for (int e = 0; e < 8; e++) ones[e] = (short)0x3F80;
  float mrunA = -1e30f, mrunB = -1e30f;
  f32x4 zero = {0.f, 0.f, 0.f, 0.f};
  f32x4 yaccA[4], yaccB[4], yonesA = zero, yonesB = zero;
#pragma unroll
  for (int ni = 0; ni < 4; ni++) { yaccA[ni] = zero; yaccB[ni] = zero; }
  const int srow = tid >> 3;
  const int schunk = tid & 7;
  const int c2 = schunk >> 2, c1 = (schunk >> 1) & 1, c0 = schunk & 1;
  const int vg1 = 4 * c2 + 2 * c0;
  const int voff = 4 * c1;

  auto kaddr = [&](int bufi, int row) -> u16* {
    return &Ks[bufi][row][(schunk ^ (row & 7)) << 3];
  };
  auto stageV = [&](int bufi, int row, u16x8 v) {
    u16x4 lo4 = __builtin_shufflevector(v, v, 0, 1, 2, 3);
    u16x4 hi4 = __builtin_shufflevector(v, v, 4, 5, 6, 7);
    *(u16x4*)&Vs[bufi][row][((vg1 ^ (row & 7)) << 3) + voff] = lo4;
    *(u16x4*)&Vs[bufi][row][(((vg1 + 1) ^ (row & 7)) << 3) + voff] = hi4;
  };
  auto qk2 = [&](int bufi, f32x4 (&sA)[4], f32x4 (&sB)[4]) {
#pragma unroll
    for (int ni = 0; ni < 4; ni++) { sA[ni] = zero; sB[ni] = zero; }
#pragma unroll
    for (int ni = 0; ni < 4; ni++) {
      int row = ni * 16 + fr;
      s16x8 kf0 = *(const s16x8*)&Ks[bufi][row][(fq ^ (fr & 7)) << 3];
      s16x8 kf1 = *(const s16x8*)&Ks[bufi][row][((4 + fq) ^ (fr & 7)) << 3];
      sA[ni] = __builtin_amdgcn_mfma_f32_16x16x32_bf16(kf0, qf0a, sA[ni], 0, 0, 0);
      sA[ni] = __builtin_amdgcn_mfma_f32_16x16x32_bf16(kf1, qf1a, sA[ni], 0, 0, 0);
      sB[ni] = __builtin_amdgcn_mfma_f32_16x16x32_bf16(kf0, qf0b, sB[ni], 0, 0, 0);
      sB[ni] = __builtin_amdgcn_mfma_f32_16x16x32_bf16(kf1, qf1b, sB[ni], 0, 0, 0);
    }
  };
  auto softmax = [&](f32x4 (&sp)[4], float& mrun, f32x4 (&yacc)[4], f32x4& yones) {
    float m0 = fmaxf(fmaxf(sp[0][0], sp[0][1]), sp[0][2]);
    float m1 = fmaxf(fmaxf(sp[0][3], sp[1][0]), sp[1][1]);
    float m2 = fmaxf(fmaxf(sp[1][2], sp[1][3]), sp[2][0]);
    float m3 = fmaxf(fmaxf(sp[2][1], sp[2][2]), sp[2][3]);
    float m4 = fmaxf(fmaxf(sp[3][0], sp[3][1]), sp[3][2]);
    float mx = fmaxf(fmaxf(fmaxf(m0, m1), m2), fmaxf(fmaxf(m3, m4), sp[3][3]));
    mx = fmaxf(mx, __shfl_xor(mx, 16, 64));
    mx = fmaxf(mx, __shfl_xor(mx, 32, 64));
    bool skip = __all(mx <= mrun + 10.0f);
    if (!skip) {
      float mn = fmaxf(mrun, mx);
      float alpha = exp2fast(mrun - mn);
      mrun = mn;
      float va[4];
#pragma unroll
      for (int r = 0; r < 4; r++) va[r] = __shfl(alpha, fq * 4 + r, 64);
#pragma unroll
      for (int ni = 0; ni < 4; ni++)
#pragma unroll
        for (int r = 0; r < 4; r++) yacc[ni][r] *= va[r];
#pragma unroll
      for (int r = 0; r < 4; r++) yones[r] *= va[r];
    }
#pragma unroll
    for (int ni = 0; ni < 4; ni++)
#pragma unroll
      for (int r = 0; r < 4; r++) sp[ni][r] = exp2fast(sp[ni][r] - mrun);
  };

  const int NT = LK_ / 64;
  f32x4 spA[4], spB[4], snA[4], snB[4];

  // prologue
  {
    u16x8 k0 = *(const u16x8*)(kbase + (size_t)srow * 64 + schunk * 8);
    u16x8 k1 = *(const u16x8*)(kbase + (size_t)(srow + 32) * 64 + schunk * 8);
    u16x8 v0 = *(const u16x8*)(vbase + (size_t)srow * LK_ + schunk * 8);
    u16x8 v1 = *(const u16x8*)(vbase + (size_t)(srow + 32) * LK_ + schunk * 8);
    *(u16x8*)kaddr(0, srow) = k0;
    *(u16x8*)kaddr(0, srow + 32) = k1;
    stageV(0, srow, v0);
    stageV(0, srow + 32, v1);
    __syncthreads();
    u16x8 ka = *(const u16x8*)(kbase + (size_t)(64 + srow) * 64 + schunk * 8);
    u16x8 kb2 = *(const u16x8*)(kbase + (size_t)(64 + srow + 32) * 64 + schunk * 8);
    u16x8 va = *(const u16x8*)(vbase + (size_t)srow * LK_ + 64 + schunk * 8);
    u16x8 vb2 = *(const u16x8*)(vbase + (size_t)(srow + 32) * LK_ + 64 + schunk * 8);
    *(u16x8*)kaddr(1, srow) = ka;
    *(u16x8*)kaddr(1, srow + 32) = kb2;
    stageV(1, srow, va);
    stageV(1, srow + 32, vb2);
    qk2(0, spA, spB);  // reads Ks[0] only
    __syncthreads();
  }

  for (int t = 0; t < NT; t++) {
    const int cur = t & 1;
    const bool st2 = (t + 2 < NT);
    u16x8 kr0, kr1, vr0, vr1;
    if (st2) {
      int kt = (t + 2) * 64;
      kr0 = *(const u16x8*)(kbase + (size_t)(kt + srow) * 64 + schunk * 8);
      kr1 = *(const u16x8*)(kbase + (size_t)(kt + srow + 32) * 64 + schunk * 8);
      vr0 = *(const u16x8*)(vbase + (size_t)srow * LK_ + kt + schunk * 8);
      vr1 = *(const u16x8*)(vbase + (size_t)(srow + 32) * LK_ + kt + schunk * 8);
    }
    if (t + 1 < NT) qk2(cur ^ 1, snA, snB);
    softmax(spA, mrunA, yaccA, yonesA);
    softmax(spB, mrunB, yaccB, yonesB);
#pragma unroll
    for (int s2 = 0; s2 < 2; s2++) {
      union { uint32_t u[4]; s16x8 v8; } puA, puB;
      puA.u[0] = cvtpk(spA[2 * s2][0], spA[2 * s2][1]);
      puA.u[1] = cvtpk(spA[2 * s2][2], spA[2 * s2][3]);
      puA.u[2] = cvtpk(spA[2 * s2 + 1][0], spA[2 * s2 + 1][1]);
      puA.u[3] = cvtpk(spA[2 * s2 + 1][2], spA[2 * s2 + 1][3]);
      puB.u[0] = cvtpk(spB[2 * s2][0], spB[2 * s2][1]);
      puB.u[1] = cvtpk(spB[2 * s2][2], spB[2 * s2][3]);
      puB.u[2] = cvtpk(spB[2 * s2 + 1][0], spB[2 * s2 + 1][1]);
      puB.u[3] = cvtpk(spB[2 * s2 + 1][2], spB[2 * s2 + 1][3]);
#pragma unroll
      for (int ni = 0; ni < 4; ni++) {
        int row = ni * 16 + fr;
        s16x8 vf = *(const s16x8*)&Vs[cur][row][(((4 * s2 + fq) ^ (fr & 7)) << 3)];
        yaccA[ni] = __builtin_amdgcn_mfma_f32_16x16x32_bf16(puA.v8, vf, yaccA[ni], 0, 0, 0);
        yaccB[ni] = __builtin_amdgcn_mfma_f32_16x16x32_bf16(puB.v8, vf, yaccB[ni], 0, 0, 0);
      }
      yonesA = __builtin_amdgcn_mfma_f32_16x16x32_bf16(puA.v8, ones, yonesA, 0, 0, 0);
      yonesB = __builtin_amdgcn_mfma_f32_16x16x32_bf16(puB.v8, ones, yonesB, 0, 0, 0);
    }
    __syncthreads();
    if (st2) {
      *(u16x8*)kaddr(cur, srow) = kr0;
      *(u16x8*)kaddr(cur, srow + 32) = kr1;
      stageV(cur, srow, vr0);
      stageV(cur, srow + 32, vr1);
    }
    __syncthreads();
#pragma unroll
    for (int ni = 0; ni < 4; ni++) { spA[ni] = snA[ni]; spB[ni] = snB[ni]; }
  }
  int b = bh >> 4, h = bh & 15;
  u16* yoA = y1 + ((size_t)(b * LQ_ + qt * 128 + wid * 32 + fq * 4)) * 1024 + h * 64;
  u16* yoB = yoA + (size_t)16 * 1024;
#pragma unroll
  for (int ni = 0; ni < 4; ni++) {
#pragma unroll
    for (int r = 0; r < 4; r++) {
      yoA[(size_t)r * 1024 + ni * 16 + fr] = f2bf(yaccA[ni][r] / yonesA[r]);
      yoB[(size_t)r * 1024 + ni * 16 + fr] = f2bf(yaccB[ni][r] / yonesB[r]);
    }
  }
}

extern "C" void kernel_launch(void* const* d_in, const int* in_sizes, int n_in,
                              void* d_out, int out_size, void* d_ws, size_t ws_size,
                              hipStream_t stream) {
  (void)in_sizes; (void)n_in; (void)out_size;
  const float* queries = (const float*)d_in[0];
  const float* kv = (const float*)d_in[1];
  const float* wq = (const float*)d_in[2];
  const float* wkv = (const float*)d_in[3];
  const float* wo = (const float*)d_in[4];
  const float* qnw = (const float*)d_in[5];
  const float* knw = (const float*)d_in[6];
  const int* pos_q = (const int*)d_in[7];
  const int* pos_k = (const int*)d_in[8];
  float* out = (float*)d_out;

  char* ws = (char*)d_ws;
  size_t off = 0;
  auto alloc = [&](size_t sz) { void* p = ws + off; off += sz; return p; };
  u16* Aq1 = (u16*)alloc((size_t)4096 * 1024 * 2);
  u16* Wqh = (u16*)alloc((size_t)1024 * 1024 * 2);
  u16* Akv1 = (u16*)alloc((size_t)8192 * 1024 * 2);
  u16* Wkvh = (u16*)alloc((size_t)2048 * 1024 * 2);
  u16* Woh = (u16*)alloc((size_t)1024 * 1024 * 2);
  u16* KVp = (u16*)alloc((size_t)8192 * 2048 * 2);
  u16* Qb = (u16*)alloc((size_t)64 * 1024 * 64 * 2);
  u16* Kb = (u16*)alloc((size_t)64 * 2048 * 64 * 2);
  u16* Vt = (u16*)alloc((size_t)64 * 2048 * 64 * 2);
  u16* Y1 = (u16*)alloc((size_t)4096 * 1024 * 2);
  float* Part = (float*)alloc((size_t)2 * 4096 * 1024 * 4);
  if (off > ws_size) return;

  const size_t PSTRIDE = (size_t)4096 * 1024;

  cast5_k<<<16384, 256, 0, stream>>>(queries, Aq1, wq, Wqh, kv, Akv1, wkv, Wkvh, wo, Woh);
  gemm_bt256<<<(8192 / 256) * (2048 / 256), 512, 0, stream>>>(Akv1, Wkvh, KVp);
  gemm_bt<<<dim3(4096 / 128, 1024 / 128, 2), 256, 0, stream>>>(Aq1, Wqh, Part, 1024);
  norm_rope_q<<<4096 * 16 / 4, 256, 0, stream>>>(Part, PSTRIDE, qnw, pos_q, Qb);
  normv_k<<<64 * 32, 256, 0, stream>>>(KVp, knw, pos_k, Kb, Vt);
  flash_k<<<64 * 8, 256, 0, stream>>>(Qb, Kb, Vt, Y1);
  gemm_bt<<<dim3(4096 / 128, 1024 / 128, 2), 256, 0, stream>>>(Y1, Woh, Part, 1024);
  reduce2_k<<<4096, 256, 0, stream>>>(Part, out, 4096 * 1024);
}